// Round 3
// baseline (204.384 us; speedup 1.0000x reference)
//
#include <hip/hip_runtime.h>
#include <stdint.h>

// Problem constants
#define N_BATCH 400000
#define BM 64                 // rows per block
#define NBLK (N_BATCH / BM)   // 6250
// d_ws layout: [0,128KB): hi bf16 weights (4 layers x 16384 ushort)
//              [128KB,256KB): lo bf16 weights
//              [256KB,+512B): bo' (folded output bias, f32[128])

typedef __bf16 bf16x8 __attribute__((ext_vector_type(8)));
typedef float  f32x4  __attribute__((ext_vector_type(4)));

__device__ __forceinline__ uint16_t f2bf(float f) {
    union { float f; uint32_t u; } x; x.f = f;
    uint32_t u = x.u;
    uint32_t r = (u + 0x7FFFu + ((u >> 16) & 1u)) >> 16;   // RNE
    return (uint16_t)r;
}
__device__ __forceinline__ float bf2f(uint16_t h) {
    union { uint32_t u; float f; } x; x.u = ((uint32_t)h) << 16;
    return x.f;
}
// swizzled element index: chan ^ ((row&7)<<3)  (works for ushort and f32 tiles)
__device__ __forceinline__ int swzi(int row, int chan) {
    return row * 128 + (chan ^ ((row & 7) << 3));
}

// ---------------- weight pack kernel (hi/lo bf16 split) ----------------
// pw[L][ks][nf][lane][j] = W_L[ks*32 + (lane>>4)*8 + j][nf*16 + (lane&15)]
// L=3 is Wo' = Wo @ blockdiag(B^T x4)
__global__ void pack_kernel(const float* __restrict__ W1, const float* __restrict__ W2,
                            const float* __restrict__ W3, const float* __restrict__ Wo,
                            const float* __restrict__ bo, const float* __restrict__ B,
                            uint16_t* __restrict__ pwh, uint16_t* __restrict__ pwl,
                            float* __restrict__ bo2) {
    if (blockIdx.x == 256) {
        int t = threadIdx.x;
        if (t < 128) {
            int dim = t >> 5, j = t & 31;
            float s = 0.f;
            for (int d = 0; d < 15; ++d) s += bo[dim * 15 + d] * B[j * 15 + d];
            bo2[t] = s;
        }
        return;
    }
    int gid = blockIdx.x * 256 + threadIdx.x;   // 0 .. 65535
    int L    = gid >> 14;
    int r    = gid & 16383;
    int j    = r & 7;
    int lane = (r >> 3) & 63;
    int nf   = (r >> 9) & 7;
    int ks   = r >> 12;
    int k = ks * 32 + (lane >> 4) * 8 + j;
    int n = nf * 16 + (lane & 15);
    float v;
    if (L == 3) {
        int dim = n >> 5, jj = n & 31;
        float s = 0.f;
        for (int d = 0; d < 15; ++d) s += Wo[k * 60 + dim * 15 + d] * B[jj * 15 + d];
        v = s;
    } else {
        const float* W = (L == 0) ? W1 : (L == 1) ? W2 : W3;
        v = W[k * 128 + n];
    }
    uint16_t h = f2bf(v);
    pwh[gid] = h;
    pwl[gid] = f2bf(v - bf2f(h));
}

// ---------------- fused main kernel ----------------
__global__ void __launch_bounds__(256) cpab_kernel(
    const float* __restrict__ x, const float* __restrict__ W0,
    const float* __restrict__ b0, const float* __restrict__ b1,
    const float* __restrict__ b2, const float* __restrict__ b3,
    const uint16_t* __restrict__ pwh, const uint16_t* __restrict__ pwl,
    const float* __restrict__ bo2,
    float* __restrict__ outz, float* __restrict__ outl)
{
    // flat LDS: 4 x 16KB bf16 H buffers; final f32 A overlays buffer-0 pair
    __shared__ __align__(16) uint8_t smem[64 * 1024 + BM * 8 * 4 + 3 * 128 * 4];
    uint16_t* Hh0 = (uint16_t*)smem;             // 16KB
    uint16_t* Hl0 = Hh0 + BM * 128;              // 16KB
    uint16_t* Hh1 = Hl0 + BM * 128;              // 16KB
    uint16_t* Hl1 = Hh1 + BM * 128;              // 16KB
    float*    Af  = (float*)Hh0;                 // overlays Hh0+Hl0 (32KB = 64x128 f32)
    float*    xblk = (float*)(smem + 64 * 1024); // 2KB
    float*    biasl = xblk + BM * 8;             // 3x128 f32

    const int tid  = threadIdx.x;
    const int blk  = blockIdx.x;
    const int lane = tid & 63;
    const int wid  = tid >> 6;
    const int ml   = lane & 15;
    const int hl   = lane >> 4;

    {
        const float2* xb = (const float2*)(x + (size_t)blk * (BM * 8));
        ((float2*)xblk)[tid] = xb[tid];
    }
    if (tid < 128) {
        biasl[0 * 128 + tid] = b1[tid];
        biasl[1 * 128 + tid] = b2[tid];
        biasl[2 * 128 + tid] = b3[tid];
    }
    __syncthreads();

    // ---- layer 0: H0 = x1 @ W0 + b0  (K=4, f32 VALU) -> Hh0/Hl0 (hi/lo split)
    {
        int j0 = (tid & 15) * 8;
        float wc[4][8], bc[8];
        #pragma unroll
        for (int k = 0; k < 4; ++k) {
            float4 lo = *(const float4*)&W0[k * 128 + j0];
            float4 hi = *(const float4*)&W0[k * 128 + j0 + 4];
            wc[k][0]=lo.x; wc[k][1]=lo.y; wc[k][2]=lo.z; wc[k][3]=lo.w;
            wc[k][4]=hi.x; wc[k][5]=hi.y; wc[k][6]=hi.z; wc[k][7]=hi.w;
        }
        {
            float4 lo = *(const float4*)&b0[j0];
            float4 hi = *(const float4*)&b0[j0 + 4];
            bc[0]=lo.x; bc[1]=lo.y; bc[2]=lo.z; bc[3]=lo.w;
            bc[4]=hi.x; bc[5]=hi.y; bc[6]=hi.z; bc[7]=hi.w;
        }
        #pragma unroll
        for (int i = 0; i < 4; ++i) {
            int row = (tid >> 4) + i * 16;
            float4 xv = *(const float4*)&xblk[row * 8];
            uint32_t pkh[4], pkl[4];
            #pragma unroll
            for (int jj = 0; jj < 8; jj += 2) {
                float v0 = bc[jj]   + xv.x*wc[0][jj]   + xv.y*wc[1][jj]   + xv.z*wc[2][jj]   + xv.w*wc[3][jj];
                float v1 = bc[jj+1] + xv.x*wc[0][jj+1] + xv.y*wc[1][jj+1] + xv.z*wc[2][jj+1] + xv.w*wc[3][jj+1];
                uint16_t h0 = f2bf(v0), h1 = f2bf(v1);
                uint16_t l0 = f2bf(v0 - bf2f(h0)), l1 = f2bf(v1 - bf2f(h1));
                pkh[jj >> 1] = (uint32_t)h0 | ((uint32_t)h1 << 16);
                pkl[jj >> 1] = (uint32_t)l0 | ((uint32_t)l1 << 16);
            }
            *(uint4*)&Hh0[swzi(row, j0)] = make_uint4(pkh[0], pkh[1], pkh[2], pkh[3]);
            *(uint4*)&Hl0[swzi(row, j0)] = make_uint4(pkl[0], pkl[1], pkl[2], pkl[3]);
        }
    }
    __syncthreads();

    // ---- 64x128x128 MFMA layer, 4-term hi/lo split (~f32 precision).
    // dstf != nullptr -> write f32 to dstf (final layer), else bf16 pair + optional relu.
    auto gemm = [&](const uint16_t* srch, const uint16_t* srcl,
                    uint16_t* dsth, uint16_t* dstl, float* dstf,
                    const uint16_t* wh, const uint16_t* wl,
                    const float* bias, bool relu) {
        f32x4 acc[4][2];
        #pragma unroll
        for (int m = 0; m < 4; ++m)
            #pragma unroll
            for (int n = 0; n < 2; ++n)
                acc[m][n] = (f32x4){0.f, 0.f, 0.f, 0.f};

        #pragma unroll
        for (int ks = 0; ks < 4; ++ks) {
            bf16x8 ah[4], al[4];
            #pragma unroll
            for (int m = 0; m < 4; ++m) {
                int idx = swzi(m * 16 + ml, ks * 32 + hl * 8);
                ah[m] = *(const bf16x8*)&srch[idx];
                al[m] = *(const bf16x8*)&srcl[idx];
            }
            #pragma unroll
            for (int n = 0; n < 2; ++n) {
                int nf = wid * 2 + n;
                int widx = ((ks * 8 + nf) * 64 + lane) * 8;
                bf16x8 bh = *(const bf16x8*)&wh[widx];
                bf16x8 bl = *(const bf16x8*)&wl[widx];
                #pragma unroll
                for (int m = 0; m < 4; ++m) {
                    // small terms first for accumulation accuracy
                    acc[m][n] = __builtin_amdgcn_mfma_f32_16x16x32_bf16(al[m], bl, acc[m][n], 0, 0, 0);
                    acc[m][n] = __builtin_amdgcn_mfma_f32_16x16x32_bf16(al[m], bh, acc[m][n], 0, 0, 0);
                    acc[m][n] = __builtin_amdgcn_mfma_f32_16x16x32_bf16(ah[m], bl, acc[m][n], 0, 0, 0);
                    acc[m][n] = __builtin_amdgcn_mfma_f32_16x16x32_bf16(ah[m], bh, acc[m][n], 0, 0, 0);
                }
            }
        }
        #pragma unroll
        for (int n = 0; n < 2; ++n) {
            int col = wid * 32 + n * 16 + ml;
            float bv = bias ? bias[col] : 0.f;
            #pragma unroll
            for (int m = 0; m < 4; ++m) {
                #pragma unroll
                for (int r = 0; r < 4; ++r) {
                    int row = m * 16 + hl * 4 + r;
                    float v = acc[m][n][r] + bv;
                    if (relu) v = fmaxf(v, 0.f);
                    int idx = swzi(row, col);
                    if (dstf) {
                        dstf[idx] = v;
                    } else {
                        uint16_t h = f2bf(v);
                        dsth[idx] = h;
                        dstl[idx] = f2bf(v - bf2f(h));
                    }
                }
            }
        }
    };

    gemm(Hh0, Hl0, Hh1, Hl1, nullptr, pwh + 0*16384, pwl + 0*16384, biasl + 0*128, true);  __syncthreads();
    gemm(Hh1, Hl1, Hh0, Hl0, nullptr, pwh + 1*16384, pwl + 1*16384, biasl + 1*128, true);  __syncthreads();
    gemm(Hh0, Hl0, Hh1, Hl1, nullptr, pwh + 2*16384, pwl + 2*16384, biasl + 2*128, true);  __syncthreads();
    // final: src = H1, dst = f32 A overlaying H0 (no overlap with src)
    gemm(Hh1, Hl1, nullptr, nullptr, Af, pwh + 3*16384, pwl + 3*16384, bo2, false);        __syncthreads();
    // Af[row][swz(dim*32 + 2c {,+1})] = (a,b) per row, dim, cell — f32.

    // ---- CPAB closed-form integration: 1 element per thread (exact ref semantics)
    {
        int row = tid >> 2, dim = tid & 3;
        float xx = xblk[row * 8 + 4 + dim];
        int c = (int)floorf(xx * 16.f);
        c = min(max(c, 0), 15);
        float t = 1.f, logg = 0.f;
        bool done = false;
        #pragma unroll 1
        for (int it = 0; it < 18; ++it) {       // nC + 2 = 18 (ref scan length)
            if (__all(done)) break;
            int ci = swzi(row, (dim << 5) + 2 * c);
            float2 ab = *(const float2*)&Af[ci];
            float a = ab.x, b = ab.y;
            float v = a * xx + b;
            bool small_a = fabsf(a) < 1e-8f;
            float a_safe = small_a ? 1.f : a;
            float eat = expf(a * t);
            float psi = small_a ? (xx + b * t) : (eat * xx + (b / a_safe) * (eat - 1.f));
            float left  = (float)c * 0.0625f;
            float right = (float)(c + 1) * 0.0625f;
            bool inside = (psi >= left) && (psi <= right);
            float xc = (v >= 0.f) ? right : left;
            float v_safe = (fabsf(v) < 1e-8f) ? 1.f : v;
            float b_safe = (fabsf(b) < 1e-8f) ? 1.f : b;
            float ratio = fmaxf((a * xc + b) / v_safe, 1e-8f);
            float thit = small_a ? ((xc - xx) / b_safe) : (logf(ratio) / a_safe);
            float tau = inside ? t : thit;
            bool new_done = done || inside;
            if (!done) {
                xx = inside ? psi : xc;
                logg = logg + a * tau;
            }
            if (!new_done) {
                t = t - thit;
                c = min(max(c + ((v >= 0.f) ? 1 : -1), 0), 15);
            }
            done = new_done;
        }
        size_t grow = (size_t)blk * BM + row;
        outz[grow * 8 + 4 + dim] = xx;
        outl[grow * 8 + 4 + dim] = logg;
        outz[grow * 8 + dim]     = xblk[row * 8 + dim];   // identity lower half
        outl[grow * 8 + dim]     = 0.f;
    }
}

extern "C" void kernel_launch(void* const* d_in, const int* in_sizes, int n_in,
                              void* d_out, int out_size, void* d_ws, size_t ws_size,
                              hipStream_t stream) {
    const float* x  = (const float*)d_in[0];
    const float* W0 = (const float*)d_in[1];
    const float* b0 = (const float*)d_in[2];
    const float* W1 = (const float*)d_in[3];
    const float* b1 = (const float*)d_in[4];
    const float* W2 = (const float*)d_in[5];
    const float* b2 = (const float*)d_in[6];
    const float* W3 = (const float*)d_in[7];
    const float* b3 = (const float*)d_in[8];
    const float* Wo = (const float*)d_in[9];
    const float* bo = (const float*)d_in[10];
    const float* B  = (const float*)d_in[11];

    uint16_t* pwh = (uint16_t*)d_ws;
    uint16_t* pwl = pwh + 4 * 16384;
    float*    bo2 = (float*)(pwl + 4 * 16384);
    float*    outz = (float*)d_out;
    float*    outl = outz + (size_t)N_BATCH * 8;

    hipLaunchKernelGGL(pack_kernel, dim3(257), dim3(256), 0, stream,
                       W1, W2, W3, Wo, bo, B, pwh, pwl, bo2);
    hipLaunchKernelGGL(cpab_kernel, dim3(NBLK), dim3(256), 0, stream,
                       x, W0, b0, b1, b2, b3, pwh, pwl, bo2, outz, outl);
}

// Round 5
// 188.026 us; speedup vs baseline: 1.0870x; 1.0870x over previous
//
#include <hip/hip_runtime.h>
#include <stdint.h>

// Problem constants
#define N_BATCH 400000
#define BM 64                 // rows per block
#define NBLK (N_BATCH / BM)   // 6250
// d_ws layout: [0,128KB): hi bf16 weights (4 layers x 16384)
//              [128KB,256KB): lo bf16 weights
//              [256KB,+512B): bo' (folded output bias, f32[128])

typedef __bf16 bf16x8 __attribute__((ext_vector_type(8)));
typedef float  f32x4  __attribute__((ext_vector_type(4)));

__device__ __forceinline__ uint16_t f2bf(float f) {
    union { float f; uint32_t u; } x; x.f = f;
    uint32_t u = x.u;
    uint32_t r = (u + 0x7FFFu + ((u >> 16) & 1u)) >> 16;   // RNE
    return (uint16_t)r;
}
__device__ __forceinline__ float bf2f(uint16_t h) {
    union { uint32_t u; float f; } x; x.u = ((uint32_t)h) << 16;
    return x.f;
}
// swizzled element index: chan ^ ((row&7)<<3)
__device__ __forceinline__ int swzi(int row, int chan) {
    return row * 128 + (chan ^ ((row & 7) << 3));
}

// ---------------- weight pack kernel (hi/lo bf16 split) ----------------
// pw[L][ks][nf][lane][j] = W_L[ks*32 + (lane>>4)*8 + j][nf*16 + (lane&15)]
// L=3 is Wo' = Wo @ blockdiag(B^T x4)
__global__ void pack_kernel(const float* __restrict__ W1, const float* __restrict__ W2,
                            const float* __restrict__ W3, const float* __restrict__ Wo,
                            const float* __restrict__ bo, const float* __restrict__ B,
                            uint16_t* __restrict__ pwh, uint16_t* __restrict__ pwl,
                            float* __restrict__ bo2) {
    if (blockIdx.x == 256) {
        int t = threadIdx.x;
        if (t < 128) {
            int dim = t >> 5, j = t & 31;
            float s = 0.f;
            for (int d = 0; d < 15; ++d) s += bo[dim * 15 + d] * B[j * 15 + d];
            bo2[t] = s;
        }
        return;
    }
    int gid = blockIdx.x * 256 + threadIdx.x;   // 0 .. 65535
    int L    = gid >> 14;
    int r    = gid & 16383;
    int j    = r & 7;
    int lane = (r >> 3) & 63;
    int nf   = (r >> 9) & 7;
    int ks   = r >> 12;
    int k = ks * 32 + (lane >> 4) * 8 + j;
    int n = nf * 16 + (lane & 15);
    float v;
    if (L == 3) {
        int dim = n >> 5, jj = n & 31;
        float s = 0.f;
        for (int d = 0; d < 15; ++d) s += Wo[k * 60 + dim * 15 + d] * B[jj * 15 + d];
        v = s;
    } else {
        const float* W = (L == 0) ? W1 : (L == 1) ? W2 : W3;
        v = W[k * 128 + n];
    }
    uint16_t h = f2bf(v);
    pwh[gid] = h;
    pwl[gid] = f2bf(v - bf2f(h));
}

// ---------------- fused main kernel ----------------
__global__ void __launch_bounds__(256) cpab_kernel(
    const float* __restrict__ x, const float* __restrict__ W0,
    const float* __restrict__ b0, const float* __restrict__ b1,
    const float* __restrict__ b2, const float* __restrict__ b3,
    const uint16_t* __restrict__ pwh, const uint16_t* __restrict__ pwl,
    const float* __restrict__ bo2,
    float* __restrict__ outz, float* __restrict__ outl)
{
    // In-place layout: single H buffer (hi 16KB + lo 16KB); f32 A overlays both.
    __shared__ __align__(16) uint8_t smem[32 * 1024 + BM * 8 * 4 + 3 * 128 * 4];
    uint16_t* Hh   = (uint16_t*)smem;              // 16KB
    uint16_t* Hl   = Hh + BM * 128;                // 16KB
    float*    Af   = (float*)smem;                 // overlays Hh+Hl (32KB = 64x128 f32)
    float*    xblk = (float*)(smem + 32 * 1024);   // 2KB
    float*    biasl = xblk + BM * 8;               // 3x128 f32

    const int tid  = threadIdx.x;
    const int blk  = blockIdx.x;
    const int lane = tid & 63;
    const int wid  = tid >> 6;
    const int ml   = lane & 15;
    const int hl   = lane >> 4;

    {
        const float2* xb = (const float2*)(x + (size_t)blk * (BM * 8));
        ((float2*)xblk)[tid] = xb[tid];
    }
    if (tid < 128) {
        biasl[0 * 128 + tid] = b1[tid];
        biasl[1 * 128 + tid] = b2[tid];
        biasl[2 * 128 + tid] = b3[tid];
    }
    __syncthreads();

    // ---- layer 0: H0 = x1 @ W0 + b0  (K=4, f32 VALU) -> Hh/Hl  (R2-exact numerics)
    {
        int j0 = (tid & 15) * 8;
        float wc[4][8], bc[8];
        #pragma unroll
        for (int k = 0; k < 4; ++k) {
            float4 lo = *(const float4*)&W0[k * 128 + j0];
            float4 hi = *(const float4*)&W0[k * 128 + j0 + 4];
            wc[k][0]=lo.x; wc[k][1]=lo.y; wc[k][2]=lo.z; wc[k][3]=lo.w;
            wc[k][4]=hi.x; wc[k][5]=hi.y; wc[k][6]=hi.z; wc[k][7]=hi.w;
        }
        {
            float4 lo = *(const float4*)&b0[j0];
            float4 hi = *(const float4*)&b0[j0 + 4];
            bc[0]=lo.x; bc[1]=lo.y; bc[2]=lo.z; bc[3]=lo.w;
            bc[4]=hi.x; bc[5]=hi.y; bc[6]=hi.z; bc[7]=hi.w;
        }
        #pragma unroll
        for (int i = 0; i < 4; ++i) {
            int row = (tid >> 4) + i * 16;
            float4 xv = *(const float4*)&xblk[row * 8];
            uint32_t pkh[4], pkl[4];
            #pragma unroll
            for (int jj = 0; jj < 8; jj += 2) {
                float v0 = bc[jj]   + xv.x*wc[0][jj]   + xv.y*wc[1][jj]   + xv.z*wc[2][jj]   + xv.w*wc[3][jj];
                float v1 = bc[jj+1] + xv.x*wc[0][jj+1] + xv.y*wc[1][jj+1] + xv.z*wc[2][jj+1] + xv.w*wc[3][jj+1];
                uint16_t h0 = f2bf(v0), h1 = f2bf(v1);
                uint16_t l0 = f2bf(v0 - bf2f(h0)), l1 = f2bf(v1 - bf2f(h1));
                pkh[jj >> 1] = (uint32_t)h0 | ((uint32_t)h1 << 16);
                pkl[jj >> 1] = (uint32_t)l0 | ((uint32_t)l1 << 16);
            }
            *(uint4*)&Hh[swzi(row, j0)] = make_uint4(pkh[0], pkh[1], pkh[2], pkh[3]);
            *(uint4*)&Hl[swzi(row, j0)] = make_uint4(pkl[0], pkl[1], pkl[2], pkl[3]);
        }
    }
    __syncthreads();

    // ---- 64x128x128 MFMA layer, 4-term hi/lo split (R2-exact numerics), IN-PLACE.
    // Every wave reads the full 64x128 src tile into registers in the MFMA loop;
    // barrier; write results back into the same buffer; barrier. Race-free.
    auto gemm = [&](const uint16_t* wh, const uint16_t* wl,
                    const float* bias, bool relu, bool final_f32) {
        f32x4 acc[4][2];
        #pragma unroll
        for (int m = 0; m < 4; ++m)
            #pragma unroll
            for (int n = 0; n < 2; ++n)
                acc[m][n] = (f32x4){0.f, 0.f, 0.f, 0.f};

        #pragma unroll
        for (int ks = 0; ks < 4; ++ks) {
            bf16x8 ah[4], al[4];
            #pragma unroll
            for (int m = 0; m < 4; ++m) {
                int idx = swzi(m * 16 + ml, ks * 32 + hl * 8);
                ah[m] = *(const bf16x8*)&Hh[idx];
                al[m] = *(const bf16x8*)&Hl[idx];
            }
            #pragma unroll
            for (int n = 0; n < 2; ++n) {
                int nf = wid * 2 + n;
                int widx = ((ks * 8 + nf) * 64 + lane) * 8;
                bf16x8 bh = *(const bf16x8*)&wh[widx];
                bf16x8 bl = *(const bf16x8*)&wl[widx];
                #pragma unroll
                for (int m = 0; m < 4; ++m) {
                    // small terms first for accumulation accuracy (R2 order)
                    acc[m][n] = __builtin_amdgcn_mfma_f32_16x16x32_bf16(al[m], bl, acc[m][n], 0, 0, 0);
                    acc[m][n] = __builtin_amdgcn_mfma_f32_16x16x32_bf16(al[m], bh, acc[m][n], 0, 0, 0);
                    acc[m][n] = __builtin_amdgcn_mfma_f32_16x16x32_bf16(ah[m], bl, acc[m][n], 0, 0, 0);
                    acc[m][n] = __builtin_amdgcn_mfma_f32_16x16x32_bf16(ah[m], bh, acc[m][n], 0, 0, 0);
                }
            }
        }
        __syncthreads();   // all reads of H complete across the block
        #pragma unroll
        for (int n = 0; n < 2; ++n) {
            int col = wid * 32 + n * 16 + ml;
            float bv = bias ? bias[col] : 0.f;
            #pragma unroll
            for (int m = 0; m < 4; ++m) {
                #pragma unroll
                for (int r = 0; r < 4; ++r) {
                    int row = m * 16 + hl * 4 + r;
                    float v = acc[m][n][r] + bv;
                    if (relu) v = fmaxf(v, 0.f);
                    int idx = swzi(row, col);
                    if (final_f32) {
                        Af[idx] = v;
                    } else {
                        uint16_t h = f2bf(v);
                        Hh[idx] = h;
                        Hl[idx] = f2bf(v - bf2f(h));
                    }
                }
            }
        }
        __syncthreads();
    };

    gemm(pwh + 0*16384, pwl + 0*16384, biasl + 0*128, true,  false);
    gemm(pwh + 1*16384, pwl + 1*16384, biasl + 1*128, true,  false);
    gemm(pwh + 2*16384, pwl + 2*16384, biasl + 2*128, true,  false);
    gemm(pwh + 3*16384, pwl + 3*16384, bo2,           false, true);
    // Af[row][swz(dim*32 + 2c {,+1})] = (a,b) per row, dim, cell — f32.

    // ---- CPAB closed-form integration: 1 element per thread (exact ref semantics)
    {
        int row = tid >> 2, dim = tid & 3;
        float xx = xblk[row * 8 + 4 + dim];
        int c = (int)floorf(xx * 16.f);
        c = min(max(c, 0), 15);
        float t = 1.f, logg = 0.f;
        bool done = false;
        #pragma unroll 1
        for (int it = 0; it < 18; ++it) {       // nC + 2 = 18 (ref scan length)
            if (__all(done)) break;
            int ci = swzi(row, (dim << 5) + 2 * c);
            float2 ab = *(const float2*)&Af[ci];
            float a = ab.x, b = ab.y;
            float v = a * xx + b;
            bool small_a = fabsf(a) < 1e-8f;
            float a_safe = small_a ? 1.f : a;
            float eat = expf(a * t);
            float psi = small_a ? (xx + b * t) : (eat * xx + (b / a_safe) * (eat - 1.f));
            float left  = (float)c * 0.0625f;
            float right = (float)(c + 1) * 0.0625f;
            bool inside = (psi >= left) && (psi <= right);
            float xc = (v >= 0.f) ? right : left;
            float v_safe = (fabsf(v) < 1e-8f) ? 1.f : v;
            float b_safe = (fabsf(b) < 1e-8f) ? 1.f : b;
            float ratio = fmaxf((a * xc + b) / v_safe, 1e-8f);
            float thit = small_a ? ((xc - xx) / b_safe) : (logf(ratio) / a_safe);
            float tau = inside ? t : thit;
            bool new_done = done || inside;
            if (!done) {
                xx = inside ? psi : xc;
                logg = logg + a * tau;
            }
            if (!new_done) {
                t = t - thit;
                c = min(max(c + ((v >= 0.f) ? 1 : -1), 0), 15);
            }
            done = new_done;
        }
        size_t grow = (size_t)blk * BM + row;
        outz[grow * 8 + 4 + dim] = xx;
        outl[grow * 8 + 4 + dim] = logg;
        outz[grow * 8 + dim]     = xblk[row * 8 + dim];   // identity lower half
        outl[grow * 8 + dim]     = 0.f;
    }
}

extern "C" void kernel_launch(void* const* d_in, const int* in_sizes, int n_in,
                              void* d_out, int out_size, void* d_ws, size_t ws_size,
                              hipStream_t stream) {
    const float* x  = (const float*)d_in[0];
    const float* W0 = (const float*)d_in[1];
    const float* b0 = (const float*)d_in[2];
    const float* W1 = (const float*)d_in[3];
    const float* b1 = (const float*)d_in[4];
    const float* W2 = (const float*)d_in[5];
    const float* b2 = (const float*)d_in[6];
    const float* W3 = (const float*)d_in[7];
    const float* b3 = (const float*)d_in[8];
    const float* Wo = (const float*)d_in[9];
    const float* bo = (const float*)d_in[10];
    const float* B  = (const float*)d_in[11];

    uint16_t* pwh = (uint16_t*)d_ws;
    uint16_t* pwl = pwh + 4 * 16384;
    float*    bo2 = (float*)(pwl + 4 * 16384);
    float*    outz = (float*)d_out;
    float*    outl = outz + (size_t)N_BATCH * 8;

    hipLaunchKernelGGL(pack_kernel, dim3(257), dim3(256), 0, stream,
                       W1, W2, W3, Wo, bo, B, pwh, pwl, bo2);
    hipLaunchKernelGGL(cpab_kernel, dim3(NBLK), dim3(256), 0, stream,
                       x, W0, b0, b1, b2, b3, pwh, pwl, bo2, outz, outl);
}

// Round 6
// 176.634 us; speedup vs baseline: 1.1571x; 1.0645x over previous
//
#include <hip/hip_runtime.h>
#include <stdint.h>

// Problem constants
#define N_BATCH 400000
#define BM 64                 // rows per block
#define NBLK (N_BATCH / BM)   // 6250
// d_ws layout: [0,128KB): hi bf16 weights (4 layers x 16384)
//              [128KB,256KB): lo bf16 weights
//              [256KB,+512B): bo' (folded output bias, f32[128])

typedef __bf16 bf16x8 __attribute__((ext_vector_type(8)));
typedef float  f32x4  __attribute__((ext_vector_type(4)));

__device__ __forceinline__ uint16_t f2bf(float f) {
    union { float f; uint32_t u; } x; x.f = f;
    uint32_t u = x.u;
    uint32_t r = (u + 0x7FFFu + ((u >> 16) & 1u)) >> 16;   // RNE
    return (uint16_t)r;
}
__device__ __forceinline__ float bf2f(uint16_t h) {
    union { uint32_t u; float f; } x; x.u = ((uint32_t)h) << 16;
    return x.f;
}
// swizzled element index: chan ^ ((row&7)<<3)
__device__ __forceinline__ int swzi(int row, int chan) {
    return row * 128 + (chan ^ ((row & 7) << 3));
}

// ---------------- weight pack kernel (hi/lo bf16 split) ----------------
// pw[L][ks][nf][lane][j] = W_L[ks*32 + (lane>>4)*8 + j][nf*16 + (lane&15)]
// L=3 is Wo' = Wo @ blockdiag(B^T x4)
__global__ void pack_kernel(const float* __restrict__ W1, const float* __restrict__ W2,
                            const float* __restrict__ W3, const float* __restrict__ Wo,
                            const float* __restrict__ bo, const float* __restrict__ B,
                            uint16_t* __restrict__ pwh, uint16_t* __restrict__ pwl,
                            float* __restrict__ bo2) {
    if (blockIdx.x == 256) {
        int t = threadIdx.x;
        if (t < 128) {
            int dim = t >> 5, j = t & 31;
            float s = 0.f;
            for (int d = 0; d < 15; ++d) s += bo[dim * 15 + d] * B[j * 15 + d];
            bo2[t] = s;
        }
        return;
    }
    int gid = blockIdx.x * 256 + threadIdx.x;   // 0 .. 65535
    int L    = gid >> 14;
    int r    = gid & 16383;
    int j    = r & 7;
    int lane = (r >> 3) & 63;
    int nf   = (r >> 9) & 7;
    int ks   = r >> 12;
    int k = ks * 32 + (lane >> 4) * 8 + j;
    int n = nf * 16 + (lane & 15);
    float v;
    if (L == 3) {
        int dim = n >> 5, jj = n & 31;
        float s = 0.f;
        for (int d = 0; d < 15; ++d) s += Wo[k * 60 + dim * 15 + d] * B[jj * 15 + d];
        v = s;
    } else {
        const float* W = (L == 0) ? W1 : (L == 1) ? W2 : W3;
        v = W[k * 128 + n];
    }
    uint16_t h = f2bf(v);
    pwh[gid] = h;
    pwl[gid] = f2bf(v - bf2f(h));
}

// ---------------- fused main kernel ----------------
__global__ void __launch_bounds__(256) cpab_kernel(
    const float* __restrict__ x, const float* __restrict__ W0,
    const float* __restrict__ b0, const float* __restrict__ b1,
    const float* __restrict__ b2, const float* __restrict__ b3,
    const __bf16* __restrict__ pwh, const __bf16* __restrict__ pwl,
    const float* __restrict__ bo2,
    float* __restrict__ outz, float* __restrict__ outl)
{
    // Exactly 32 KB LDS: H hi/lo planes; f32 A overlays both. 5 blocks/CU.
    __shared__ __align__(16) uint8_t smem[32 * 1024];
    __bf16* Hh = (__bf16*)smem;                // 16KB
    __bf16* Hl = Hh + BM * 128;                // 16KB
    float*  Af = (float*)smem;                 // overlays Hh+Hl (64x128 f32)

    const int tid  = threadIdx.x;
    const int blk  = blockIdx.x;
    const int lane = tid & 63;
    const int wid  = tid >> 6;
    const int ml   = lane & 15;
    const int hl   = lane >> 4;
    const float* xrow = x + (size_t)blk * (BM * 8);

    // ---- layer 0: H0 = x1 @ W0 + b0  (K=4, f32 VALU) -> Hh/Hl
    // (numerics identical to R2: f32 FMA chain, RNE hi/lo split)
    {
        int j0 = (tid & 15) * 8;
        float wc[4][8], bc[8];
        #pragma unroll
        for (int k = 0; k < 4; ++k) {
            float4 lo = *(const float4*)&W0[k * 128 + j0];
            float4 hi = *(const float4*)&W0[k * 128 + j0 + 4];
            wc[k][0]=lo.x; wc[k][1]=lo.y; wc[k][2]=lo.z; wc[k][3]=lo.w;
            wc[k][4]=hi.x; wc[k][5]=hi.y; wc[k][6]=hi.z; wc[k][7]=hi.w;
        }
        {
            float4 lo = *(const float4*)&b0[j0];
            float4 hi = *(const float4*)&b0[j0 + 4];
            bc[0]=lo.x; bc[1]=lo.y; bc[2]=lo.z; bc[3]=lo.w;
            bc[4]=hi.x; bc[5]=hi.y; bc[6]=hi.z; bc[7]=hi.w;
        }
        #pragma unroll
        for (int i = 0; i < 4; ++i) {
            int row = (tid >> 4) + i * 16;
            float4 xv = *(const float4*)&xrow[row * 8];
            bf16x8 hv, lv;
            #pragma unroll
            for (int jj = 0; jj < 8; ++jj) {
                float v = bc[jj] + xv.x*wc[0][jj] + xv.y*wc[1][jj] + xv.z*wc[2][jj] + xv.w*wc[3][jj];
                __bf16 h = (__bf16)v;          // HW RNE cast == f2bf
                hv[jj] = h;
                lv[jj] = (__bf16)(v - (float)h);
            }
            int idx = swzi(row, j0);
            *(bf16x8*)&Hh[idx] = hv;
            *(bf16x8*)&Hl[idx] = lv;
        }
    }
    __syncthreads();

    // ---- 64x128x128 MFMA layer, 4-term hi/lo split (R2-exact numerics), IN-PLACE.
    auto gemm = [&](const __bf16* wh, const __bf16* wl,
                    const float* bias, bool relu, bool final_f32) {
        // bias: 2 scalar global loads, issued early (L2-hot)
        float bv0 = bias[wid * 32 + 0  + ml];
        float bv1 = bias[wid * 32 + 16 + ml];

        f32x4 acc[4][2];
        #pragma unroll
        for (int m = 0; m < 4; ++m)
            #pragma unroll
            for (int n = 0; n < 2; ++n)
                acc[m][n] = (f32x4){0.f, 0.f, 0.f, 0.f};

        __builtin_amdgcn_s_setprio(1);
        #pragma unroll
        for (int ks = 0; ks < 4; ++ks) {
            bf16x8 ah[4], al[4];
            #pragma unroll
            for (int m = 0; m < 4; ++m) {
                int idx = swzi(m * 16 + ml, ks * 32 + hl * 8);
                ah[m] = *(const bf16x8*)&Hh[idx];
                al[m] = *(const bf16x8*)&Hl[idx];
            }
            #pragma unroll
            for (int n = 0; n < 2; ++n) {
                int nf = wid * 2 + n;
                int widx = ((ks * 8 + nf) * 64 + lane) * 8;
                bf16x8 bh = *(const bf16x8*)&wh[widx];
                bf16x8 bl = *(const bf16x8*)&wl[widx];
                #pragma unroll
                for (int m = 0; m < 4; ++m) {
                    // small terms first for accumulation accuracy (R2 order)
                    acc[m][n] = __builtin_amdgcn_mfma_f32_16x16x32_bf16(al[m], bl, acc[m][n], 0, 0, 0);
                    acc[m][n] = __builtin_amdgcn_mfma_f32_16x16x32_bf16(al[m], bh, acc[m][n], 0, 0, 0);
                    acc[m][n] = __builtin_amdgcn_mfma_f32_16x16x32_bf16(ah[m], bl, acc[m][n], 0, 0, 0);
                    acc[m][n] = __builtin_amdgcn_mfma_f32_16x16x32_bf16(ah[m], bh, acc[m][n], 0, 0, 0);
                }
            }
        }
        __builtin_amdgcn_s_setprio(0);
        __syncthreads();   // all reads of H complete across the block
        #pragma unroll
        for (int n = 0; n < 2; ++n) {
            int col = wid * 32 + n * 16 + ml;
            float bv = n ? bv1 : bv0;
            #pragma unroll
            for (int m = 0; m < 4; ++m) {
                #pragma unroll
                for (int r = 0; r < 4; ++r) {
                    int row = m * 16 + hl * 4 + r;
                    float v = acc[m][n][r] + bv;
                    if (relu) v = fmaxf(v, 0.f);
                    int idx = swzi(row, col);
                    if (final_f32) {
                        Af[idx] = v;
                    } else {
                        __bf16 h = (__bf16)v;   // HW RNE cast == f2bf
                        Hh[idx] = h;
                        Hl[idx] = (__bf16)(v - (float)h);
                    }
                }
            }
        }
        __syncthreads();
    };

    gemm(pwh + 0*16384, pwl + 0*16384, b1,  true,  false);
    gemm(pwh + 1*16384, pwl + 1*16384, b2,  true,  false);
    gemm(pwh + 2*16384, pwl + 2*16384, b3,  true,  false);
    gemm(pwh + 3*16384, pwl + 3*16384, bo2, false, true);
    // Af[row][swz(dim*32 + 2c {,+1})] = (a,b) per row, dim, cell — f32.

    // ---- CPAB closed-form integration: 1 element per thread (exact ref semantics)
    {
        int row = tid >> 2, dim = tid & 3;
        float xx = xrow[row * 8 + 4 + dim];
        int c = (int)floorf(xx * 16.f);
        c = min(max(c, 0), 15);
        float t = 1.f, logg = 0.f;
        bool done = false;
        #pragma unroll 1
        for (int it = 0; it < 18; ++it) {       // nC + 2 = 18 (ref scan length)
            if (__all(done)) break;
            int ci = swzi(row, (dim << 5) + 2 * c);
            float2 ab = *(const float2*)&Af[ci];
            float a = ab.x, b = ab.y;
            float v = a * xx + b;
            bool small_a = fabsf(a) < 1e-8f;
            float a_safe = small_a ? 1.f : a;
            float eat = expf(a * t);
            float psi = small_a ? (xx + b * t) : (eat * xx + (b / a_safe) * (eat - 1.f));
            float left  = (float)c * 0.0625f;
            float right = (float)(c + 1) * 0.0625f;
            bool inside = (psi >= left) && (psi <= right);
            float xc = (v >= 0.f) ? right : left;
            float v_safe = (fabsf(v) < 1e-8f) ? 1.f : v;
            float b_safe = (fabsf(b) < 1e-8f) ? 1.f : b;
            float ratio = fmaxf((a * xc + b) / v_safe, 1e-8f);
            float thit = small_a ? ((xc - xx) / b_safe) : (logf(ratio) / a_safe);
            float tau = inside ? t : thit;
            bool new_done = done || inside;
            if (!done) {
                xx = inside ? psi : xc;
                logg = logg + a * tau;
            }
            if (!new_done) {
                t = t - thit;
                c = min(max(c + ((v >= 0.f) ? 1 : -1), 0), 15);
            }
            done = new_done;
        }
        size_t grow = (size_t)blk * BM + row;
        outz[grow * 8 + 4 + dim] = xx;
        outl[grow * 8 + 4 + dim] = logg;
        outz[grow * 8 + dim]     = xrow[row * 8 + dim];   // identity lower half
        outl[grow * 8 + dim]     = 0.f;
    }
}

extern "C" void kernel_launch(void* const* d_in, const int* in_sizes, int n_in,
                              void* d_out, int out_size, void* d_ws, size_t ws_size,
                              hipStream_t stream) {
    const float* x  = (const float*)d_in[0];
    const float* W0 = (const float*)d_in[1];
    const float* b0 = (const float*)d_in[2];
    const float* W1 = (const float*)d_in[3];
    const float* b1 = (const float*)d_in[4];
    const float* W2 = (const float*)d_in[5];
    const float* b2 = (const float*)d_in[6];
    const float* W3 = (const float*)d_in[7];
    const float* b3 = (const float*)d_in[8];
    const float* Wo = (const float*)d_in[9];
    const float* bo = (const float*)d_in[10];
    const float* B  = (const float*)d_in[11];

    uint16_t* pwh = (uint16_t*)d_ws;
    uint16_t* pwl = pwh + 4 * 16384;
    float*    bo2 = (float*)(pwl + 4 * 16384);
    float*    outz = (float*)d_out;
    float*    outl = outz + (size_t)N_BATCH * 8;

    hipLaunchKernelGGL(pack_kernel, dim3(257), dim3(256), 0, stream,
                       W1, W2, W3, Wo, bo, B, pwh, pwl, bo2);
    hipLaunchKernelGGL(cpab_kernel, dim3(NBLK), dim3(256), 0, stream,
                       x, W0, b0, b1, b2, b3,
                       (const __bf16*)pwh, (const __bf16*)pwl, bo2, outz, outl);
}